// Round 7
// baseline (264.736 us; speedup 1.0000x reference)
//
#include <hip/hip_runtime.h>
#include <hip/hip_bf16.h>
#include <stdint.h>

typedef __hip_bfloat16 bf16;
typedef __attribute__((ext_vector_type(8))) short short8;
typedef __attribute__((ext_vector_type(4))) float float4v;

#define NVOCAB 113
#define NPAIR (113 * 113)   // 12769
#define DDIM 128
#define HIDDIM 512

// fp32 pool: only tok/pos/b1/b2 now
#define OFF_TOK 0
#define OFF_POS 14464
#define OFF_B1  14720
#define OFF_B2  15232
#define WFTOTAL 15360

// bf16 transposed weight pool wb (element offsets)
#define BOFF_WOT 0                         // WOT[n][c] = W_O[c*128+n]    128x128
#define BOFF_W1T 16384                     // W1T[n][d] = W1[d*512+n]     512x128
#define BOFF_W2T (16384 + 65536)           // W2T[n][j] = W2[j*128+n]     128x512
#define BOFF_WUP (16384 + 65536 + 65536)   // WUP[v][d] = W_U[v*128+d]|0  128x128
#define BTOTAL   (16384 + 65536 + 65536 + 16384)  // 163840
#define QTOTAL   49152                     // qw[which][h*32+j][d]
#define PREP_TOTAL (BTOTAL + QTOTAL + WFTOTAL)    // 228352

__device__ __forceinline__ uint16_t f2b(float f) {
  bf16 h = __float2bfloat16(f);
  return *(uint16_t*)&h;
}
__device__ __forceinline__ float b2f(uint16_t u) {
  return __uint_as_float(((uint32_t)u) << 16);
}

// ---------------- runtime dtype detection ----------------
__global__ void detect_kernel(const uint32_t* __restrict__ tok_raw,
                              const uint32_t* __restrict__ x_raw,
                              int* __restrict__ flags) {
  __shared__ int cnt_bf16, cnt_xnz;
  if (threadIdx.x == 0) { cnt_bf16 = 0; cnt_xnz = 0; }
  __syncthreads();
  uint32_t u = tok_raw[threadIdx.x];
  int e = (u >> 7) & 0xff;
  if (e >= 100 && e <= 126) atomicAdd(&cnt_bf16, 1);
  uint32_t xv = x_raw[2 * threadIdx.x + 1];
  if (xv != 0u) atomicAdd(&cnt_xnz, 1);
  __syncthreads();
  if (threadIdx.x == 0) {
    flags[0] = (cnt_bf16 >= 128) ? 1 : 0;   // float tensors are bf16
    flags[1] = (cnt_xnz == 0) ? 1 : 0;      // x is int64
  }
}

// ---------------- fused prep: raw -> wb (bf16 transposed), qw, wf ----------
struct SrcPtrs { const void* p[11]; };
// p[0]=tok p[1]=pos p[2]=WQ p[3]=WK p[4]=WV p[5]=WO p[6]=W1 p[7]=b1 p[8]=W2
// p[9]=b2 p[10]=WU

__device__ __forceinline__ float ldf(const void* src, int i, int isbf) {
  return isbf ? b2f(((const uint16_t*)src)[i]) : ((const float*)src)[i];
}

__global__ void prep_kernel(SrcPtrs sp, uint16_t* __restrict__ wb,
                            uint16_t* __restrict__ qw,
                            float* __restrict__ wf,
                            const int* __restrict__ flags) {
  const int idx = blockIdx.x * 256 + threadIdx.x;
  if (idx >= PREP_TOTAL) return;
  const int isbf = flags[0];
  if (idx < BOFF_W1T) {                     // WOT[n][c] = WO[c*128+n]
    int n = idx >> 7, c = idx & 127;
    wb[idx] = f2b(ldf(sp.p[5], c * 128 + n, isbf));
  } else if (idx < BOFF_W2T) {              // W1T[n][d] = W1[d*512+n]
    int l = idx - BOFF_W1T, n = l >> 7, d = l & 127;
    wb[idx] = f2b(ldf(sp.p[6], d * 512 + n, isbf));
  } else if (idx < BOFF_WUP) {              // W2T[n][j] = W2[j*128+n]
    int l = idx - BOFF_W2T, n = l >> 9, j = l & 511;
    wb[idx] = f2b(ldf(sp.p[8], j * 128 + n, isbf));
  } else if (idx < BTOTAL) {                // WUP[v][d] = WU[v*128+d] | 0
    int l = idx - BOFF_WUP, vv = l >> 7, d = l & 127;
    wb[idx] = (vv < NVOCAB) ? f2b(ldf(sp.p[10], vv * 128 + d, isbf)) : 0;
  } else if (idx < BTOTAL + QTOTAL) {       // qw[which][h*32+j][d]
    int l = idx - BTOTAL;
    int which = l >> 14, r = l & 16383;
    int hj = r >> 7, d = r & 127;
    int h = hj >> 5, j = hj & 31;
    qw[l] = f2b(ldf(sp.p[2 + which], h * 4096 + d * 32 + j, isbf));
  } else {                                  // fp32 pool: tok|pos|b1|b2
    int l = idx - (BTOTAL + QTOTAL);
    if (l < 14464)       wf[OFF_TOK + l] = ldf(sp.p[0], l, isbf);
    else if (l < 14720)  wf[OFF_POS + l - 14464] = ldf(sp.p[1], l - 14464, isbf);
    else if (l < 15232)  wf[OFF_B1 + l - 14720] = ldf(sp.p[7], l - 14720, isbf);
    else                 wf[OFF_B2 + l - 15232] = ldf(sp.p[9], l - 15232, isbf);
  }
}

// ---------------- Phase A: embeddings + q/k/v (transposed bf16 weights) -----
__global__ void __launch_bounds__(384) qkv_kernel(
    const float* __restrict__ wf, const uint16_t* __restrict__ qw,
    float* __restrict__ resid_pre, float* __restrict__ qt,
    float* __restrict__ kt, float* __restrict__ vt) {
  const int row = blockIdx.x;
  const int t = row >> 1, p = row & 1;
  const int tid = threadIdx.x;

  __shared__ float r[DDIM];
  if (tid < DDIM) {
    float rv = wf[OFF_TOK + t * DDIM + tid] + wf[OFF_POS + p * DDIM + tid];
    r[tid] = rv;
    resid_pre[row * DDIM + tid] = rv;
  }
  __syncthreads();

  const int which = tid >> 7, j = tid & 127;
  const short8* wrow = (const short8*)(qw + which * 16384 + j * 128);
  float a = 0.f;
  #pragma unroll
  for (int ch = 0; ch < 16; ++ch) {
    short8 wv = wrow[ch];
    #pragma unroll
    for (int e = 0; e < 8; ++e)
      a += r[ch * 8 + e] * b2f((uint16_t)wv[e]);
  }
  float* outp = (which == 0) ? qt : (which == 1) ? kt : vt;
  outp[row * DDIM + j] = a;
}

// ---------------- Phase B: fused MFMA kernel, 8 pairs (16 rows) / block -----
// LDS swizzle: element [m][k] at (m*CH + ((k>>3) ^ (m&15)))*8 + (k&7), CH=K/8
// MFMA 16x16x32 bf16 maps: A: lane=A[m=lane&15][k=quad*8+j];
//   B: lane=B[k=quad*8+j][n=lane&15];  D: reg r = D[row=quad*4+r][col=lane&15]
__global__ void __launch_bounds__(256, 4) pair_mfma_kernel(
    const float* __restrict__ resid_pre, const float* __restrict__ qt,
    const float* __restrict__ kt, const float* __restrict__ vt,
    const float* __restrict__ wf, const uint16_t* __restrict__ wb,
    uint16_t* __restrict__ table) {
  __shared__ uint16_t bufH[16 * 512];   // H staging (CH=64), 16 KB
  __shared__ uint16_t bufZ[16 * 128];   // Z, then R (CH=16), 4 KB
  __shared__ uint16_t bufS[16 * 128];   // smid bf16 (CH=16), 4 KB
  __shared__ float    spat[8 * 16];
  __shared__ int      srow[16];

  const int tid = threadIdx.x;
  const int blk = blockIdx.x;

  // ---- prologue: scores ----
  if (tid < 128) {
    const int pl = tid >> 4, s = tid & 15;
    const int pair = blk * 8 + pl;
    if (pair < NPAIR) {
      const int t0 = pair / NVOCAB, t1 = pair - t0 * NVOCAB;
      const int row0 = t0 * 2, row1 = t1 * 2 + 1;
      const int h = s >> 2, qp = (s >> 1) & 1, sp = s & 1;
      const float4* qrow = (const float4*)(qt + (qp ? row1 : row0) * DDIM + h * 32);
      const float4* krow = (const float4*)(kt + (sp ? row1 : row0) * DDIM + h * 32);
      float acc = 0.f;
      #pragma unroll
      for (int j = 0; j < 8; ++j) {
        float4 qv = qrow[j], kv = krow[j];
        acc += qv.x * kv.x + qv.y * kv.y + qv.z * kv.z + qv.w * kv.w;
      }
      spat[pl * 16 + s] = acc * 0.17677669529663687f;
    } else {
      spat[pl * 16 + s] = 0.f;
    }
  } else if (tid < 144) {
    const int m = tid - 128;
    const int pair = blk * 8 + (m >> 1);
    int rv = 0;
    if (pair < NPAIR) {
      const int t0 = pair / NVOCAB, t1 = pair - t0 * NVOCAB;
      rv = (m & 1) ? t1 * 2 + 1 : t0 * 2;
    }
    srow[m] = rv;
  }
  __syncthreads();
  // ---- softmax + blend ----
  if (tid < 64) {
    const int pl = tid >> 3, s = tid & 7;
    const int base = pl * 16 + s * 2;
    float s0 = spat[base], s1 = spat[base + 1];
    float m = fmaxf(s0, s1);
    float e0 = __expf(s0 - m), e1 = __expf(s1 - m);
    float inv = 1.f / (e0 + e1);
    spat[base]     = 0.5f + 0.5f * e0 * inv;
    spat[base + 1] = 0.5f + 0.5f * e1 * inv;
  }
  __syncthreads();
  // ---- Z = pattern-weighted V, staged bf16 ----
  {
    const int m = tid >> 4, c0 = (tid & 15) * 8;
    const int pl = m >> 1, qp = m & 1;
    const int row0 = srow[pl * 2], row1 = srow[pl * 2 + 1];
    const int h = c0 >> 5;
    const float p0 = spat[pl * 16 + h * 4 + qp * 2];
    const float p1 = spat[pl * 16 + h * 4 + qp * 2 + 1];
    short8 pk;
    #pragma unroll
    for (int e = 0; e < 8; ++e) {
      const int c = c0 + e;
      float z = p0 * vt[row0 * DDIM + c] + p1 * vt[row1 * DDIM + c];
      pk[e] = (short)f2b(z);
    }
    *(short8*)&bufZ[(m * 16 + ((c0 >> 3) ^ m)) * 8] = pk;
  }
  __syncthreads();

  const int lane = tid & 63;
  const int npar = tid >> 6;            // wave id = N-partition 0..3
  const int l15 = lane & 15, quad = lane >> 4;
  const int mA = l15;

  float smid[2][4];                     // residual mid kept in registers

  // ---- GEMM0: smid = Z x WOT + resid  (N=128, K=128) ----
  {
    short8 af[4];
    #pragma unroll
    for (int ks = 0; ks < 4; ++ks)
      af[ks] = *(const short8*)&bufZ[(mA * 16 + ((ks * 4 + quad) ^ mA)) * 8];
    #pragma unroll
    for (int ni = 0; ni < 2; ++ni) {
      const int n = (npar + ni * 4) * 16 + l15;
      const uint16_t* bp = wb + BOFF_WOT + n * 128 + quad * 8;
      float4v acc = {0.f, 0.f, 0.f, 0.f};
      #pragma unroll
      for (int ks = 0; ks < 4; ++ks)
        acc = __builtin_amdgcn_mfma_f32_16x16x32_bf16(
            af[ks], *(const short8*)(bp + ks * 32), acc, 0, 0, 0);
      #pragma unroll
      for (int r = 0; r < 4; ++r) {
        const int row = quad * 4 + r;
        float v = acc[r] + resid_pre[srow[row] * DDIM + n];
        smid[ni][r] = v;
        bufS[(row * 16 + ((n >> 3) ^ row)) * 8 + (n & 7)] = f2b(v);
      }
    }
  }
  __syncthreads();

  // ---- GEMM1: H = relu(smid x W1 + b1)  (N=512, K=128) ----
  {
    short8 af[4];
    #pragma unroll
    for (int ks = 0; ks < 4; ++ks)
      af[ks] = *(const short8*)&bufS[(mA * 16 + ((ks * 4 + quad) ^ mA)) * 8];
    #pragma unroll
    for (int ni = 0; ni < 8; ++ni) {
      const int n = (npar + ni * 4) * 16 + l15;
      const uint16_t* bp = wb + BOFF_W1T + n * 128 + quad * 8;
      float4v acc = {0.f, 0.f, 0.f, 0.f};
      #pragma unroll
      for (int ks = 0; ks < 4; ++ks)
        acc = __builtin_amdgcn_mfma_f32_16x16x32_bf16(
            af[ks], *(const short8*)(bp + ks * 32), acc, 0, 0, 0);
      const float bias = wf[OFF_B1 + n];
      #pragma unroll
      for (int r = 0; r < 4; ++r) {
        const int row = quad * 4 + r;
        bufH[(row * 64 + ((n >> 3) ^ row)) * 8 + (n & 7)] =
            f2b(fmaxf(acc[r] + bias, 0.f));
      }
    }
  }
  __syncthreads();

  // ---- GEMM2: R = smid + H x W2 + b2  (N=128, K=512) ----
  {
    short8 ah[16];
    #pragma unroll
    for (int ks = 0; ks < 16; ++ks)
      ah[ks] = *(const short8*)&bufH[(mA * 64 + ((ks * 4 + quad) ^ mA)) * 8];
    #pragma unroll
    for (int ni = 0; ni < 2; ++ni) {
      const int n = (npar + ni * 4) * 16 + l15;
      const uint16_t* bp = wb + BOFF_W2T + n * 512 + quad * 8;
      float4v acc = {0.f, 0.f, 0.f, 0.f};
      #pragma unroll
      for (int ks = 0; ks < 16; ++ks)
        acc = __builtin_amdgcn_mfma_f32_16x16x32_bf16(
            ah[ks], *(const short8*)(bp + ks * 32), acc, 0, 0, 0);
      const float bias = wf[OFF_B2 + n];
      #pragma unroll
      for (int r = 0; r < 4; ++r) {
        const int row = quad * 4 + r;
        bufZ[(row * 16 + ((n >> 3) ^ row)) * 8 + (n & 7)] =
            f2b(acc[r] + bias + smid[ni][r]);
      }
    }
  }
  __syncthreads();

  // ---- GEMM3: logits = R x WUP^T, store bf16 table ----
  {
    short8 ar[4];
    #pragma unroll
    for (int ks = 0; ks < 4; ++ks)
      ar[ks] = *(const short8*)&bufZ[(mA * 16 + ((ks * 4 + quad) ^ mA)) * 8];
    #pragma unroll
    for (int ni = 0; ni < 2; ++ni) {
      const int n = (npar + ni * 4) * 16 + l15;
      const uint16_t* bp = wb + BOFF_WUP + n * 128 + quad * 8;
      float4v acc = {0.f, 0.f, 0.f, 0.f};
      #pragma unroll
      for (int ks = 0; ks < 4; ++ks)
        acc = __builtin_amdgcn_mfma_f32_16x16x32_bf16(
            ar[ks], *(const short8*)(bp + ks * 32), acc, 0, 0, 0);
      if (n < NVOCAB) {
        #pragma unroll
        for (int r = 0; r < 4; ++r) {
          const int row = quad * 4 + r;
          const int pair = blk * 8 + (row >> 1);
          if (pair < NPAIR)
            table[pair * 226 + (row & 1) * NVOCAB + n] = f2b(acc[r]);
        }
      }
    }
  }
}

// ---------------- Phase C: gather, bf16 table -> fp32 out --------------------
// block = 256 threads handles 2 output rows; row = 113 uint32 (226 bf16)
__global__ void __launch_bounds__(256) gather_kernel(
    const uint32_t* __restrict__ x_raw, const uint32_t* __restrict__ table_u32,
    float2* __restrict__ out_v2, int B, const int* __restrict__ flags) {
  __shared__ int pbase[2];
  const int tid = threadIdx.x;
  const int b0 = blockIdx.x * 2;
  if (tid < 2) {
    const int b = b0 + tid;
    int pair = 0;
    if (b < B) {
      int t0, t1;
      if (flags[1]) { t0 = (int)x_raw[4 * b]; t1 = (int)x_raw[4 * b + 2]; }
      else          { t0 = (int)x_raw[2 * b]; t1 = (int)x_raw[2 * b + 1]; }
      t0 = min(max(t0, 0), NVOCAB - 1);
      t1 = min(max(t1, 0), NVOCAB - 1);
      pair = t0 * NVOCAB + t1;
    }
    pbase[tid] = pair * NVOCAB;
  }
  __syncthreads();
  const int half = tid >> 7, j = tid & 127;
  const int b = b0 + half;
  if (j < NVOCAB && b < B) {
    uint32_t u = table_u32[pbase[half] + j];
    float2 o;
    o.x = __uint_as_float(u << 16);
    o.y = __uint_as_float(u & 0xffff0000u);
    out_v2[b * NVOCAB + j] = o;
  }
}

extern "C" void kernel_launch(void* const* d_in, const int* in_sizes, int n_in,
                              void* d_out, int out_size, void* d_ws, size_t ws_size,
                              hipStream_t stream) {
  // ws layout (byte offsets)
  int*      flags     = (int*)d_ws;                            // 256 B
  float*    wf        = (float*)((char*)d_ws + 256);           // 61440 B
  float*    resid_pre = (float*)((char*)d_ws + 61952);
  float*    qt        = (float*)((char*)d_ws + 177664);
  float*    kt        = (float*)((char*)d_ws + 293376);
  float*    vt        = (float*)((char*)d_ws + 409088);
  uint16_t* wb        = (uint16_t*)((char*)d_ws + 524800);     // 327680 B
  uint16_t* qw        = (uint16_t*)((char*)d_ws + 852480);     // 98304 B
  uint16_t* table     = (uint16_t*)((char*)d_ws + 950784);     // 5771588 B

  const int B = in_sizes[0] / 2;

  detect_kernel<<<1, 256, 0, stream>>>((const uint32_t*)d_in[1],
                                       (const uint32_t*)d_in[0], flags);

  SrcPtrs sp;
  for (int i = 0; i < 11; ++i) sp.p[i] = d_in[i + 1];
  prep_kernel<<<(PREP_TOTAL + 255) / 256, 256, 0, stream>>>(sp, wb, qw, wf,
                                                            flags);

  qkv_kernel<<<226, 384, 0, stream>>>(wf, qw, resid_pre, qt, kt, vt);

  const int nblk = (NPAIR + 7) / 8;  // 1597
  pair_mfma_kernel<<<nblk, 256, 0, stream>>>(resid_pre, qt, kt, vt, wf, wb,
                                             table);

  gather_kernel<<<(B + 1) / 2, 256, 0, stream>>>(
      (const uint32_t*)d_in[0], (const uint32_t*)table, (float2*)d_out,
      B, flags);
}